// Round 21
// baseline (51.222 us; speedup 1.0000x reference)
//
#include <hip/hip_runtime.h>

typedef float f32x4 __attribute__((ext_vector_type(4)));
typedef __bf16 bf16x8 __attribute__((ext_vector_type(8)));
typedef unsigned short u16x8 __attribute__((ext_vector_type(8)));

static constexpr int B_ = 8, Cin = 128, Cout = 128, K2 = 9;
static constexpr int HW  = 64 * 64;      // 4096
static constexpr int CHW = Cin * HW;     // 524288
static constexpr int KC  = Cin * K2;     // 1152
static constexpr int SLD = 136;          // LDS row stride (u16), 272B

static __device__ __forceinline__ unsigned short f2bf(float f) {
  unsigned int u = __builtin_bit_cast(unsigned int, f);
  u = u + 0x7fffu + ((u >> 16) & 1u);
  return (unsigned short)(u >> 16);
}
static __device__ __forceinline__ float b2f_lo(unsigned int u) {
  return __builtin_bit_cast(float, u << 16);
}
static __device__ __forceinline__ float b2f_hi(unsigned int u) {
  return __builtin_bit_cast(float, u & 0xffff0000u);
}
static __device__ __forceinline__ unsigned cvt_pk_bf16(float lo, float hi) {
  unsigned r;
  asm("v_cvt_pk_bf16_f32 %0, %1, %2" : "=v"(r) : "v"(lo), "v"(hi));
  return r;
}

// ---------------- kernel 1: prep + transpose + xt guard rows ----------------
// wsW2:  [w(8)][k(9)][ks(4)][lane(64)][j(8)]  deform W, lane-contiguous A-frags
// wOffB2:[r(9)][ks(4)][m(2)][lane(64)][j(8)]  offset W (oc pad 18->32)
// xt has a 256B zero guard row before and after (selector-free edge handling).
__global__ __launch_bounds__(256) void prep_trans_kernel(
    const float* __restrict__ x, const float* __restrict__ dw,
    const float* __restrict__ ow, unsigned short* __restrict__ wsW2,
    unsigned short* __restrict__ wOffB2, unsigned short* __restrict__ xt) {
  int bid = blockIdx.x;
  int t = threadIdx.x;

  // ---- transpose part: block (b,y) ----
  int swz = (bid & 7) * 64 + (bid >> 3);
  int b = swz >> 6, y = swz & 63;
  int lane = t & 63, cq = t >> 6;
  __shared__ unsigned short L[64 * SLD];
  const float* xb = x + b * CHW + y * 64;
#pragma unroll
  for (int i = 0; i < 32; ++i) {
    int c = i * 4 + cq;
    L[lane * SLD + c] = f2bf(xb[c * HW + lane]);
  }
  __syncthreads();
  int p = t >> 2, q = t & 3;
  unsigned short* op = xt + (size_t)b * HW * 128 + y * 64 * 128 + p * 128 + q * 32;
#pragma unroll
  for (int s = 0; s < 4; ++s)
    *(u16x8*)(op + s * 8) = *(const u16x8*)&L[p * SLD + q * 32 + s * 8];

  // ---- guard rows (zeroed every launch) ----
  if (bid == 0 && t < 128) {
    xt[-128 + t] = 0;                       // front guard (256 B)
    xt[(size_t)8 * HW * 128 + t] = 0;       // rear guard (256 B)
  }

  // ---- prep part (grid-strided) ----
  for (int i = bid * 256 + t; i < 8 * 9 * 4 * 512; i += 512 * 256) {
    int j = i & 7, ln = (i >> 3) & 63, ks = (i >> 9) & 3, t2 = i >> 11;
    int k = t2 % 9, w = t2 / 9;
    int oc = w * 16 + (ln & 15);
    int c = ks * 32 + (ln >> 4) * 8 + j;
    wsW2[i] = f2bf(dw[(oc * Cin + c) * K2 + k]);
  }
  {
    int i = bid * 256 + t;
    if (i < 9 * 4 * 2 * 512) {
      int j = i & 7, ln = (i >> 3) & 63, m = (i >> 9) & 1, t3 = i >> 10;
      int ks = t3 & 3, r = t3 >> 2;
      int oc = m * 16 + (ln & 15);
      int c = ks * 32 + (ln >> 4) * 8 + j;
      wOffB2[i] = (oc < 18) ? f2bf(ow[(oc * Cin + c) * K2 + r]) : (unsigned short)0;
    }
  }
}

// ---------------- kernel 2: fused offset-conv + records + deform GEMM + BN/SiLU ----
__global__ __launch_bounds__(512, 4) void fused_kernel(
    const unsigned short* __restrict__ xt, const unsigned short* __restrict__ wsW2,
    const unsigned short* __restrict__ wOffB2, const float* __restrict__ ob,
    const float* __restrict__ dbias, const float* __restrict__ gamma,
    const float* __restrict__ beta, const float* __restrict__ mean,
    const float* __restrict__ var, float* __restrict__ out) {
  int bid = blockIdx.x;
  int swz = (bid & 7) * 64 + (bid >> 3);           // XCD i <- batch i
  int b = swz >> 6, ho = swz & 63;
  int t = threadIdx.x;
  int lane = t & 63, wv = t >> 6;
  int col = lane & 15, g = lane >> 4;

  __shared__ unsigned short SAB[2][64 * SLD];      // 34816 B
  __shared__ float T[64 * 20];                     //  5120 B offsets [pos][oc]
  __shared__ float RW4[576 * 4];                   //  9216 B f32 bilinear weights
  __shared__ unsigned RI[576];                     //  2304 B packed offsets (+1 biased)

  const unsigned short* xtb = xt + (size_t)b * HW * 128;
  const unsigned int* xtb32 = (const unsigned int*)xtb;

  // ---------- phase A: offset conv (staged, coalesced) ----------
  auto stageA = [&](int r, int buf) {
    int ky = r / 3, kx = r % 3;
    int yv = ho + ky - 1;
    bool oky = (unsigned)yv < 64u;
    int yc = min(max(yv, 0), 63);
#pragma unroll
    for (int rr = 0; rr < 8; ++rr) {
      int p = wv * 8 + rr;
      int xc = p + kx - 1;
      bool ok = oky && ((unsigned)xc < 64u);
      int xcc = min(max(xc, 0), 63);
      unsigned v = ok ? xtb32[(yc * 64 + xcc) * 64 + lane] : 0u;
      *(unsigned*)&SAB[buf][p * SLD + 2 * lane] = v;
    }
  };

  f32x4 accO = (f32x4){0.f, 0.f, 0.f, 0.f};
  int mA = wv >> 2, nA = wv & 3;                   // all 8 waves compute

  stageA(0, 0);
  __syncthreads();
  for (int r = 0; r < 9; ++r) {
    int cur = r & 1;
    if (r < 8) stageA(r + 1, cur ^ 1);
#pragma unroll
    for (int ks = 0; ks < 4; ++ks) {
      bf16x8 bfr = *(const bf16x8*)&SAB[cur][(nA * 16 + col) * SLD + ks * 32 + g * 8];
      u16x8 af = *(const u16x8*)(wOffB2 + ((r * 4 + ks) * 2 + mA) * 512 + lane * 8);
      accO = __builtin_amdgcn_mfma_f32_16x16x32_bf16(
          __builtin_bit_cast(bf16x8, af), bfr, accO, 0, 0, 0);
    }
    __syncthreads();
  }
  {                                                // D -> T[pos][oc] with bias
#pragma unroll
    for (int rg = 0; rg < 4; ++rg) {
      int row = mA * 16 + g * 4 + rg;
      if (row < 18) T[(nA * 16 + col) * 20 + row] = accO[rg] + ob[row];
    }
  }
  __syncthreads();

  // ---------- phase B: bilinear records (selector-free, f32 weights) ----------
#pragma unroll
  for (int it = 0; it < 2; ++it) {
    int idx = it * 64 + lane;
    if (idx < 72) {
      int k = idx >> 3, rr = idx & 7;
      int pp = wv * 8 + rr;
      float dy = T[pp * 20 + 2 * k], dx = T[pp * 20 + 2 * k + 1];
      float py = (float)(ho - 1 + k / 3) + dy;
      float px = (float)(pp - 1 + k % 3) + dx;
      float y0f = floorf(py), x0f = floorf(px);
      float wy1 = py - y0f, wy0 = 1.f - wy1;
      float wx1 = px - x0f, wx0 = 1.f - wx1;
      int y0 = (int)y0f, x0 = (int)x0f;
      bool vy0 = (unsigned)y0 < 64u, vy1 = (unsigned)(y0 + 1) < 64u;
      bool vx0 = (unsigned)x0 < 64u, vx1 = (unsigned)(x0 + 1) < 64u;
      float w00 = (vy0 && vx0) ? wy0 * wx0 : 0.f;
      float w01 = (vy0 && vx1) ? wy0 * wx1 : 0.f;
      float w10 = (vy1 && vx0) ? wy1 * wx0 : 0.f;
      float w11 = (vy1 && vx1) ? wy1 * wx1 : 0.f;
      int y0c = min(max(y0, 0), 63), y1c = min(max(y0 + 1, 0), 63);
      int x0c = min(max(x0, -1), 63);              // -1..63; invalid corners weight 0
      unsigned o0p = (unsigned)(y0c * 64 + x0c + 1);   // +1 biased, 0..4096
      unsigned o1p = (unsigned)(y1c * 64 + x0c + 1);
      int ridx = k * 64 + pp;
      RI[ridx] = o0p | (o1p << 13);
      RW4[ridx * 4 + 0] = w00; RW4[ridx * 4 + 1] = w01;
      RW4[ridx * 4 + 2] = w10; RW4[ridx * 4 + 3] = w11;
    }
  }
  __syncthreads();

  // ---------- phase C: deformable GEMM (2-deep gather prefetch) ----------
  f32x4 acc[4];
#pragma unroll
  for (int j = 0; j < 4; ++j) acc[j] = (f32x4){0.f, 0.f, 0.f, 0.f};
  const unsigned short* wA = wsW2 + wv * (9 * 4 * 512) + lane * 8;

  auto combineRec = [&](int ridx, unsigned c00, unsigned c01,
                        unsigned c10, unsigned c11) -> unsigned {
    float4 w4 = *(const float4*)&RW4[ridx * 4];
    float lo = w4.x * b2f_lo(c00) + w4.y * b2f_lo(c01) +
               w4.z * b2f_lo(c10) + w4.w * b2f_lo(c11);
    float hi = w4.x * b2f_hi(c00) + w4.y * b2f_hi(c01) +
               w4.z * b2f_hi(c10) + w4.w * b2f_hi(c11);
    return cvt_pk_bf16(lo, hi);
  };

  auto issueGather = [&](int kk, unsigned (&c00)[8], unsigned (&c01)[8],
                         unsigned (&c10)[8], unsigned (&c11)[8]) {
#pragma unroll
    for (int r = 0; r < 8; ++r) {
      int ridx = kk * 64 + wv * 8 + r;
      unsigned pk = RI[ridx];
      int o0 = (int)(pk & 8191) - 1, o1 = (int)((pk >> 13) & 8191) - 1;
      const unsigned int* r0 = xtb32 + o0 * 64;
      const unsigned int* r1 = xtb32 + o1 * 64;
      c00[r] = r0[lane]; c01[r] = r0[lane + 64];
      c10[r] = r1[lane]; c11[r] = r1[lane + 64];
    }
  };

  unsigned A00[8], A01[8], A10[8], A11[8];         // gather set A
  unsigned B00[8], B01[8], B10[8], B11[8];         // gather set B
  u16x8 afA[4], afB[4];

#pragma unroll
  for (int ks = 0; ks < 4; ++ks)
    afA[ks] = *(const u16x8*)(wA + ks * 512);      // A-frags k=0

  {                                                // prologue: stage k=0
    issueGather(0, A00, A01, A10, A11);
#pragma unroll
    for (int r = 0; r < 8; ++r) {
      *(unsigned*)&SAB[0][(wv * 8 + r) * SLD + 2 * lane] =
          combineRec(wv * 8 + r, A00[r], A01[r], A10[r], A11[r]);
    }
    issueGather(1, A00, A01, A10, A11);            // k=1 corners -> set A
  }
  __syncthreads();

  // body: iteration k. Gc holds corners for k+1 (issued at k-1, landed);
  // Gn receives corners for k+2; afC = A-frags k, afN <- A-frags k+1.
  auto body = [&](int k, u16x8 (&afC)[4], u16x8 (&afN)[4],
                  unsigned (&Gc00)[8], unsigned (&Gc01)[8],
                  unsigned (&Gc10)[8], unsigned (&Gc11)[8],
                  unsigned (&Gn00)[8], unsigned (&Gn01)[8],
                  unsigned (&Gn10)[8], unsigned (&Gn11)[8]) {
    int cur = k & 1;
    if (k <= 6) issueGather(k + 2, Gn00, Gn01, Gn10, Gn11);
    if (k < 8) {
#pragma unroll
      for (int ks = 0; ks < 4; ++ks)
        afN[ks] = *(const u16x8*)(wA + ((k + 1) * 4 + ks) * 512);
    }
#pragma unroll
    for (int pt = 0; pt < 4; ++pt) {               // MFMA cluster pt ...
#pragma unroll
      for (int ks = 0; ks < 4; ++ks) {
        bf16x8 bfr = *(const bf16x8*)&SAB[cur][(pt * 16 + col) * SLD + ks * 32 + g * 8];
        acc[pt] = __builtin_amdgcn_mfma_f32_16x16x32_bf16(
            __builtin_bit_cast(bf16x8, afC[ks]), bfr, acc[pt], 0, 0, 0);
      }
      if (k < 8) {                                 // ... overlapped with 2-rec combine
#pragma unroll
        for (int rh = 0; rh < 2; ++rh) {
          int r = pt * 2 + rh;
          int ridx = (k + 1) * 64 + wv * 8 + r;
          *(unsigned*)&SAB[cur ^ 1][(wv * 8 + r) * SLD + 2 * lane] =
              combineRec(ridx, Gc00[r], Gc01[r], Gc10[r], Gc11[r]);
        }
      }
    }
    __syncthreads();
  };

  for (int kk = 0; kk < 8; kk += 2) {
    body(kk,     afA, afB, A00, A01, A10, A11, B00, B01, B10, B11);
    body(kk + 1, afB, afA, B00, B01, B10, B11, A00, A01, A10, A11);
  }
  body(8, afA, afB, A00, A01, A10, A11, B00, B01, B10, B11);

  // epilogue: bias + BN + SiLU, write NCHW
  float* op = out + b * (Cout * HW) + ho * 64;
  int ocb = wv * 16 + g * 4;
#pragma unroll
  for (int r = 0; r < 4; ++r) {
    int oc = ocb + r;
    float sc = gamma[oc] * rsqrtf(var[oc] + 1e-5f);
    float bs = beta[oc] - mean[oc] * sc;
    float db = dbias[oc];
#pragma unroll
    for (int pt = 0; pt < 4; ++pt) {
      float v = (acc[pt][r] + db) * sc + bs;
      op[oc * HW + pt * 16 + col] = v / (1.f + __expf(-v));
    }
  }
}

extern "C" void kernel_launch(void* const* d_in, const int* in_sizes, int n_in,
                              void* d_out, int out_size, void* d_ws, size_t ws_size,
                              hipStream_t stream) {
  const float* x     = (const float*)d_in[0];
  const float* ow    = (const float*)d_in[1];
  const float* ob    = (const float*)d_in[2];
  const float* dw    = (const float*)d_in[3];
  const float* db    = (const float*)d_in[4];
  const float* gamma = (const float*)d_in[5];
  const float* beta  = (const float*)d_in[6];
  const float* mean  = (const float*)d_in[7];
  const float* var   = (const float*)d_in[8];

  char* wsc = (char*)d_ws;
  unsigned short* wsW2   = (unsigned short*)wsc;               // 294912 B
  unsigned short* wOffB2 = (unsigned short*)(wsc + 294912);    // 73728 B
  // [368640, 368896): front guard; xt data; then 256B rear guard
  unsigned short* xt     = (unsigned short*)(wsc + 368896);    // 8388608 B + guards

  prep_trans_kernel<<<512, 256, 0, stream>>>(x, dw, ow, wsW2, wOffB2, xt);
  fused_kernel<<<512, 512, 0, stream>>>(xt, wsW2, wOffB2, ob, db, gamma, beta,
                                        mean, var, (float*)d_out);
}

// Round 22
// 49.587 us; speedup vs baseline: 1.0330x; 1.0330x over previous
//
#include <hip/hip_runtime.h>

typedef float f32x4 __attribute__((ext_vector_type(4)));
typedef __bf16 bf16x8 __attribute__((ext_vector_type(8)));
typedef unsigned short u16x8 __attribute__((ext_vector_type(8)));

static constexpr int B_ = 8, Cin = 128, Cout = 128, K2 = 9;
static constexpr int HW  = 64 * 64;      // 4096
static constexpr int CHW = Cin * HW;     // 524288
static constexpr int KC  = Cin * K2;     // 1152
static constexpr int SLD = 136;          // LDS row stride (u16), 272B

static __device__ __forceinline__ unsigned short f2bf(float f) {
  unsigned int u = __builtin_bit_cast(unsigned int, f);
  u = u + 0x7fffu + ((u >> 16) & 1u);
  return (unsigned short)(u >> 16);
}
static __device__ __forceinline__ float b2f_lo(unsigned int u) {
  return __builtin_bit_cast(float, u << 16);
}
static __device__ __forceinline__ float b2f_hi(unsigned int u) {
  return __builtin_bit_cast(float, u & 0xffff0000u);
}
static __device__ __forceinline__ unsigned cvt_pk_bf16(float lo, float hi) {
  unsigned r;
  asm("v_cvt_pk_bf16_f32 %0, %1, %2" : "=v"(r) : "v"(lo), "v"(hi));
  return r;
}

// ---------------- kernel 1: prep + transpose + xt guard rows ----------------
// wsW2:  [w(8)][k(9)][ks(4)][lane(64)][j(8)]  deform W, lane-contiguous A-frags
// wOffB2:[r(9)][ks(4)][m(2)][lane(64)][j(8)]  offset W (oc pad 18->32)
// xt has a 256B zero guard row before and after (selector-free edge handling).
__global__ __launch_bounds__(256) void prep_trans_kernel(
    const float* __restrict__ x, const float* __restrict__ dw,
    const float* __restrict__ ow, unsigned short* __restrict__ wsW2,
    unsigned short* __restrict__ wOffB2, unsigned short* __restrict__ xt) {
  int bid = blockIdx.x;
  int t = threadIdx.x;

  // ---- transpose part: block (b,y) ----
  int swz = (bid & 7) * 64 + (bid >> 3);
  int b = swz >> 6, y = swz & 63;
  int lane = t & 63, cq = t >> 6;
  __shared__ unsigned short L[64 * SLD];
  const float* xb = x + b * CHW + y * 64;
#pragma unroll
  for (int i = 0; i < 32; ++i) {
    int c = i * 4 + cq;
    L[lane * SLD + c] = f2bf(xb[c * HW + lane]);
  }
  __syncthreads();
  int p = t >> 2, q = t & 3;
  unsigned short* op = xt + (size_t)b * HW * 128 + y * 64 * 128 + p * 128 + q * 32;
#pragma unroll
  for (int s = 0; s < 4; ++s)
    *(u16x8*)(op + s * 8) = *(const u16x8*)&L[p * SLD + q * 32 + s * 8];

  // ---- guard rows (zeroed every launch) ----
  if (bid == 0 && t < 128) {
    xt[-128 + t] = 0;                       // front guard (256 B)
    xt[(size_t)8 * HW * 128 + t] = 0;       // rear guard (256 B)
  }

  // ---- prep part (grid-strided) ----
  for (int i = bid * 256 + t; i < 8 * 9 * 4 * 512; i += 512 * 256) {
    int j = i & 7, ln = (i >> 3) & 63, ks = (i >> 9) & 3, t2 = i >> 11;
    int k = t2 % 9, w = t2 / 9;
    int oc = w * 16 + (ln & 15);
    int c = ks * 32 + (ln >> 4) * 8 + j;
    wsW2[i] = f2bf(dw[(oc * Cin + c) * K2 + k]);
  }
  {
    int i = bid * 256 + t;
    if (i < 9 * 4 * 2 * 512) {
      int j = i & 7, ln = (i >> 3) & 63, m = (i >> 9) & 1, t3 = i >> 10;
      int ks = t3 & 3, r = t3 >> 2;
      int oc = m * 16 + (ln & 15);
      int c = ks * 32 + (ln >> 4) * 8 + j;
      wOffB2[i] = (oc < 18) ? f2bf(ow[(oc * Cin + c) * K2 + r]) : (unsigned short)0;
    }
  }
}

// ---------------- kernel 2: fused offset-conv + records + deform GEMM + BN/SiLU ----
__global__ __launch_bounds__(512, 4) void fused_kernel(
    const unsigned short* __restrict__ xt, const unsigned short* __restrict__ wsW2,
    const unsigned short* __restrict__ wOffB2, const float* __restrict__ ob,
    const float* __restrict__ dbias, const float* __restrict__ gamma,
    const float* __restrict__ beta, const float* __restrict__ mean,
    const float* __restrict__ var, float* __restrict__ out) {
  int bid = blockIdx.x;
  int swz = (bid & 7) * 64 + (bid >> 3);           // XCD i <- batch i
  int b = swz >> 6, ho = swz & 63;
  int t = threadIdx.x;
  int lane = t & 63, wv = t >> 6;
  int col = lane & 15, g = lane >> 4;

  __shared__ unsigned short SAB[2][64 * SLD];      // 34816 B
  __shared__ float T[64 * 20];                     //  5120 B offsets [pos][oc]
  __shared__ float RW4[576 * 4];                   //  9216 B f32 bilinear weights
  __shared__ unsigned RI[576];                     //  2304 B packed offsets (+1 biased)

  const unsigned short* xtb = xt + (size_t)b * HW * 128;
  const unsigned int* xtb32 = (const unsigned int*)xtb;

  // ---------- phase A: offset conv (staged, coalesced) ----------
  auto stageA = [&](int r, int buf) {
    int ky = r / 3, kx = r % 3;
    int yv = ho + ky - 1;
    bool oky = (unsigned)yv < 64u;
    int yc = min(max(yv, 0), 63);
#pragma unroll
    for (int rr = 0; rr < 8; ++rr) {
      int p = wv * 8 + rr;
      int xc = p + kx - 1;
      bool ok = oky && ((unsigned)xc < 64u);
      int xcc = min(max(xc, 0), 63);
      unsigned v = ok ? xtb32[(yc * 64 + xcc) * 64 + lane] : 0u;
      *(unsigned*)&SAB[buf][p * SLD + 2 * lane] = v;
    }
  };

  f32x4 accO = (f32x4){0.f, 0.f, 0.f, 0.f};
  int mA = wv >> 2, nA = wv & 3;                   // all 8 waves compute

  stageA(0, 0);
  __syncthreads();
  for (int r = 0; r < 9; ++r) {
    int cur = r & 1;
    if (r < 8) stageA(r + 1, cur ^ 1);
#pragma unroll
    for (int ks = 0; ks < 4; ++ks) {
      bf16x8 bfr = *(const bf16x8*)&SAB[cur][(nA * 16 + col) * SLD + ks * 32 + g * 8];
      u16x8 af = *(const u16x8*)(wOffB2 + ((r * 4 + ks) * 2 + mA) * 512 + lane * 8);
      accO = __builtin_amdgcn_mfma_f32_16x16x32_bf16(
          __builtin_bit_cast(bf16x8, af), bfr, accO, 0, 0, 0);
    }
    __syncthreads();
  }
  {                                                // D -> T[pos][oc] with bias
#pragma unroll
    for (int rg = 0; rg < 4; ++rg) {
      int row = mA * 16 + g * 4 + rg;
      if (row < 18) T[(nA * 16 + col) * 20 + row] = accO[rg] + ob[row];
    }
  }
  __syncthreads();

  // ---------- phase B: bilinear records (selector-free, f32 weights) ----------
#pragma unroll
  for (int it = 0; it < 2; ++it) {
    int idx = it * 64 + lane;
    if (idx < 72) {
      int k = idx >> 3, rr = idx & 7;
      int pp = wv * 8 + rr;
      float dy = T[pp * 20 + 2 * k], dx = T[pp * 20 + 2 * k + 1];
      float py = (float)(ho - 1 + k / 3) + dy;
      float px = (float)(pp - 1 + k % 3) + dx;
      float y0f = floorf(py), x0f = floorf(px);
      float wy1 = py - y0f, wy0 = 1.f - wy1;
      float wx1 = px - x0f, wx0 = 1.f - wx1;
      int y0 = (int)y0f, x0 = (int)x0f;
      bool vy0 = (unsigned)y0 < 64u, vy1 = (unsigned)(y0 + 1) < 64u;
      bool vx0 = (unsigned)x0 < 64u, vx1 = (unsigned)(x0 + 1) < 64u;
      float w00 = (vy0 && vx0) ? wy0 * wx0 : 0.f;
      float w01 = (vy0 && vx1) ? wy0 * wx1 : 0.f;
      float w10 = (vy1 && vx0) ? wy1 * wx0 : 0.f;
      float w11 = (vy1 && vx1) ? wy1 * wx1 : 0.f;
      int y0c = min(max(y0, 0), 63), y1c = min(max(y0 + 1, 0), 63);
      int x0c = min(max(x0, -1), 63);              // -1..63; invalid corners weight 0
      unsigned o0p = (unsigned)(y0c * 64 + x0c + 1);   // +1 biased, 0..4096
      unsigned o1p = (unsigned)(y1c * 64 + x0c + 1);
      int ridx = k * 64 + pp;
      RI[ridx] = o0p | (o1p << 13);
      RW4[ridx * 4 + 0] = w00; RW4[ridx * 4 + 1] = w01;
      RW4[ridx * 4 + 2] = w10; RW4[ridx * 4 + 3] = w11;
    }
  }
  __syncthreads();

  // ---------- phase C: deformable GEMM (MFMA/combine interleaved) ----------
  f32x4 acc[4];
#pragma unroll
  for (int j = 0; j < 4; ++j) acc[j] = (f32x4){0.f, 0.f, 0.f, 0.f};
  const unsigned short* wA = wsW2 + wv * (9 * 4 * 512) + lane * 8;

  auto combineRec = [&](int ridx, unsigned c00, unsigned c01,
                        unsigned c10, unsigned c11) -> unsigned {
    float4 w4 = *(const float4*)&RW4[ridx * 4];
    float lo = w4.x * b2f_lo(c00) + w4.y * b2f_lo(c01) +
               w4.z * b2f_lo(c10) + w4.w * b2f_lo(c11);
    float hi = w4.x * b2f_hi(c00) + w4.y * b2f_hi(c01) +
               w4.z * b2f_hi(c10) + w4.w * b2f_hi(c11);
    return cvt_pk_bf16(lo, hi);
  };

  u16x8 afc[4], afn[4];
#pragma unroll
  for (int ks = 0; ks < 4; ++ks)
    afc[ks] = *(const u16x8*)(wA + ks * 512);      // A-frags k=0

  {                                                // prologue: stage k=0
#pragma unroll
    for (int r = 0; r < 8; ++r) {
      int pp = wv * 8 + r, ridx = pp;
      unsigned pk = RI[ridx];
      int o0 = (int)(pk & 8191) - 1, o1 = (int)((pk >> 13) & 8191) - 1;
      const unsigned int* r0 = xtb32 + o0 * 64;
      const unsigned int* r1 = xtb32 + o1 * 64;
      unsigned c00 = r0[lane], c01 = r0[lane + 64];
      unsigned c10 = r1[lane], c11 = r1[lane + 64];
      *(unsigned*)&SAB[0][pp * SLD + 2 * lane] = combineRec(ridx, c00, c01, c10, c11);
    }
  }
  __syncthreads();

  for (int k = 0; k < 9; ++k) {
    int cur = k & 1;
    unsigned c00[8], c01[8], c10[8], c11[8];
    if (k < 8) {                                   // issue k+1 gathers + A-frags early
#pragma unroll
      for (int r = 0; r < 8; ++r) {
        int ridx = (k + 1) * 64 + wv * 8 + r;
        unsigned pk = RI[ridx];
        int o0 = (int)(pk & 8191) - 1, o1 = (int)((pk >> 13) & 8191) - 1;
        const unsigned int* r0 = xtb32 + o0 * 64;
        const unsigned int* r1 = xtb32 + o1 * 64;
        c00[r] = r0[lane]; c01[r] = r0[lane + 64];
        c10[r] = r1[lane]; c11[r] = r1[lane + 64];
      }
#pragma unroll
      for (int ks = 0; ks < 4; ++ks)
        afn[ks] = *(const u16x8*)(wA + ((k + 1) * 4 + ks) * 512);
    }
#pragma unroll
    for (int pt = 0; pt < 4; ++pt) {               // MFMA cluster pt ...
#pragma unroll
      for (int ks = 0; ks < 4; ++ks) {
        bf16x8 bfr = *(const bf16x8*)&SAB[cur][(pt * 16 + col) * SLD + ks * 32 + g * 8];
        acc[pt] = __builtin_amdgcn_mfma_f32_16x16x32_bf16(
            __builtin_bit_cast(bf16x8, afc[ks]), bfr, acc[pt], 0, 0, 0);
      }
      if (k < 8) {                                 // ... overlapped with 2-rec combine
#pragma unroll
        for (int rh = 0; rh < 2; ++rh) {
          int r = pt * 2 + rh;
          int ridx = (k + 1) * 64 + wv * 8 + r;
          *(unsigned*)&SAB[cur ^ 1][(wv * 8 + r) * SLD + 2 * lane] =
              combineRec(ridx, c00[r], c01[r], c10[r], c11[r]);
        }
      }
    }
    if (k < 8) {
#pragma unroll
      for (int ks = 0; ks < 4; ++ks) afc[ks] = afn[ks];
    }
    __syncthreads();
  }

  // epilogue: bias + BN + SiLU, write NCHW
  float* op = out + b * (Cout * HW) + ho * 64;
  int ocb = wv * 16 + g * 4;
#pragma unroll
  for (int r = 0; r < 4; ++r) {
    int oc = ocb + r;
    float sc = gamma[oc] * rsqrtf(var[oc] + 1e-5f);
    float bs = beta[oc] - mean[oc] * sc;
    float db = dbias[oc];
#pragma unroll
    for (int pt = 0; pt < 4; ++pt) {
      float v = (acc[pt][r] + db) * sc + bs;
      op[oc * HW + pt * 16 + col] = v / (1.f + __expf(-v));
    }
  }
}

extern "C" void kernel_launch(void* const* d_in, const int* in_sizes, int n_in,
                              void* d_out, int out_size, void* d_ws, size_t ws_size,
                              hipStream_t stream) {
  const float* x     = (const float*)d_in[0];
  const float* ow    = (const float*)d_in[1];
  const float* ob    = (const float*)d_in[2];
  const float* dw    = (const float*)d_in[3];
  const float* db    = (const float*)d_in[4];
  const float* gamma = (const float*)d_in[5];
  const float* beta  = (const float*)d_in[6];
  const float* mean  = (const float*)d_in[7];
  const float* var   = (const float*)d_in[8];

  char* wsc = (char*)d_ws;
  unsigned short* wsW2   = (unsigned short*)wsc;               // 294912 B
  unsigned short* wOffB2 = (unsigned short*)(wsc + 294912);    // 73728 B
  // [368640, 368896): front guard; xt data; then 256B rear guard
  unsigned short* xt     = (unsigned short*)(wsc + 368896);    // 8388608 B + guards

  prep_trans_kernel<<<512, 256, 0, stream>>>(x, dw, ow, wsW2, wOffB2, xt);
  fused_kernel<<<512, 512, 0, stream>>>(xt, wsW2, wOffB2, ob, db, gamma, beta,
                                        mean, var, (float*)d_out);
}